// Round 28
// baseline (756.405 us; speedup 1.0000x reference)
//
#include <hip/hip_runtime.h>
#include <hip/hip_bf16.h>

#define E_ 32
#define DIM_ 2048
#define INTER_ 1408
#define UP_ 2816
#define NT_ 4096
#define NE_ 16384
#define MAXT 96   // row-tiles of 256: sum ceil(gs_e/256) <= 16384/256 + 32 = 96

typedef __attribute__((ext_vector_type(8))) short bf16x8;
typedef __attribute__((ext_vector_type(4))) float f32x4;
typedef unsigned int uint32;
typedef unsigned long long u64t;

struct Meta {
  int gs[E_];
  int offs[E_ + 1];
  int Ttot;
  int ntiles;
  int tile_e[MAXT];
  int tile_r0[MAXT];
};

__device__ __forceinline__ unsigned short bf16_of(float f) {
  union { __hip_bfloat16 b; unsigned short u; } cv;
  cv.b = __float2bfloat16(f);
  return cv.u;
}

__device__ __forceinline__ bool mask_ok(const void* m, int mode, int tok) {
  if (mode) return ((const uint32*)m)[tok] != 0u;
  return ((const unsigned char*)m)[tok] != 0;
}

// ---------------- fused: block 0 = routing sort; blocks 1.. = x f32->bf16 cast ----------------
__global__ __launch_bounds__(256) void k_route_cast(
    const void* __restrict__ tmask, const float* __restrict__ wts,
    const int* __restrict__ idx, Meta* __restrict__ meta,
    int* __restrict__ s_tok, float* __restrict__ s_prob, int* __restrict__ inv,
    const float* __restrict__ x, unsigned short* __restrict__ xb) {
  const int t = threadIdx.x;
  if (blockIdx.x != 0) {  // ---- xcast part ----
    const size_t i = ((size_t)(blockIdx.x - 1) * 256 + t) * 8;
    f32x4 a = *(const f32x4*)(x + i);
    f32x4 b = *(const f32x4*)(x + i + 4);
    uint4 o;
    o.x = (uint32)bf16_of(a.x) | ((uint32)bf16_of(a.y) << 16);
    o.y = (uint32)bf16_of(a.z) | ((uint32)bf16_of(a.w) << 16);
    o.z = (uint32)bf16_of(b.x) | ((uint32)bf16_of(b.y) << 16);
    o.w = (uint32)bf16_of(b.z) | ((uint32)bf16_of(b.w) << 16);
    *(uint4*)(xb + i) = o;
    return;
  }
  // ---- routing part (block 0 only) ----
  __shared__ unsigned short tc[E_][257];
  __shared__ int offs_s[E_ + 1];
  __shared__ int tot[E_];
  __shared__ int mmode;
  if (t == 0) {
    const uint32* w = (const uint32*)tmask;
    bool word_mode = true;
    for (int i = 0; i < 64; ++i) {
      uint32 v = w[i];
      if (!(v <= 1u || v == 0x3F800000u)) { word_mode = false; break; }
    }
    mmode = word_mode ? 1 : 0;
  }
#pragma unroll
  for (int e = 0; e < E_; ++e) tc[e][t] = 0;
  __syncthreads();
  const int base = t * 64;
  for (int i = 0; i < 64; ++i) {
    int ent = base + i;
    int e = idx[ent];
    bool v = mask_ok(tmask, mmode, ent >> 2) && (e >= 0) && (e < E_);
    if (v) tc[e][t] += 1;
  }
  __syncthreads();
  if (t < E_) {
    int run = 0;
    for (int j = 0; j < 256; ++j) {
      int c = tc[t][j]; tc[t][j] = (unsigned short)run; run += c;
    }
    tot[t] = run;
  }
  __syncthreads();
  if (t == 0) {
    int acc = 0, nt = 0;
    for (int e = 0; e < E_; ++e) {
      offs_s[e] = acc;
      meta->offs[e] = acc;
      meta->gs[e] = tot[e];
      for (int r0 = 0; r0 < tot[e]; r0 += 256) {
        meta->tile_e[nt] = e; meta->tile_r0[nt] = r0; ++nt;
      }
      acc += tot[e];
    }
    offs_s[E_] = acc;
    meta->offs[E_] = acc;
    meta->Ttot = acc;
    meta->ntiles = nt;
  }
  __syncthreads();
  for (int i = 0; i < 64; ++i) {
    int ent = base + i;
    int e = idx[ent];
    bool v = mask_ok(tmask, mmode, ent >> 2) && (e >= 0) && (e < E_);
    if (v) {
      int r = tc[e][t]++;
      int pos = offs_s[e] + r;
      s_tok[pos] = ent >> 2;
      s_prob[pos] = wts[ent];
      inv[ent] = pos;
    } else {
      inv[ent] = -1;
    }
  }
}

// ---------------- grouped GEMM: 256x128 tile, BK=64, counted-vmcnt (T4) ----------------
// Champion (r13/r16/r18/r20/r22-r27 lineage): GEMM1 444us, VGPR 96, no spills.
// Ledger: 10 surgeries, 1 win (counted vmcnt(4)), 8 losses, 1 null. Sharp
// local optimum of the 2-barrier family — do not perturb.
template <int KTOT, int NTOT, bool GEGLU, bool GATHER>
__global__ __launch_bounds__(512) void k_gemm(
    const float* __restrict__ Wf, const float* __restrict__ scale,
    const unsigned short* __restrict__ Asrc, const Meta* __restrict__ meta,
    const int* __restrict__ s_tok, const float* __restrict__ s_prob,
    unsigned short* __restrict__ o_bf16, float* __restrict__ o_f32, int staged) {
  constexpr int NX = NTOT / 128;
  constexpr int NKS = KTOT / 64;   // 32 (GEMM1), 22 (GEMM2): even, >= 4
  const int NBact = NX * meta->ntiles;
  const int bid = blockIdx.x;
  if (bid >= NBact) return;
  const int q = NBact >> 3, r = NBact & 7;
  const int x = bid & 7, pos = bid >> 3;
  const int wk = ((x < r) ? x * (q + 1) : r * (q + 1) + (x - r) * q) + pos;
  const int tile = wk / NX;
  const int n0 = (wk % NX) * 128;
  const int e = meta->tile_e[tile];
  const int row0 = meta->tile_r0[tile];
  const int off = meta->offs[e];
  const int gsz = meta->gs[e];

  __shared__ unsigned short As[256 * 64];
  __shared__ unsigned short Bs[128 * 64];

  const int tid = threadIdx.x;
  const int lane = tid & 63;
  const int wid = tid >> 6;
  const int wm = wid >> 1;
  const int wn = wid & 1;

  // ---- A gather source pointers (pre-swizzled global, linear LDS dest) ----
  const char* aSrc[4];
  {
    const int rr = lane >> 3, cc = lane & 7;
#pragma unroll
    for (int i = 0; i < 4; ++i) {
      const int grow = row0 + wid * 32 + i * 8 + rr;
      int slot;
      if (GATHER) slot = (grow < gsz) ? s_tok[off + grow] : 0;
      else slot = off + grow;
      const int key = rr ^ ((wid * 4 + i) & 7);
      aSrc[i] = (const char*)Asrc + (size_t)slot * (KTOT * 2) + ((cc ^ key) << 4);
    }
  }

  // ---- B staging role: thread -> (4 consecutive k, 4 n) ----
  const int kq = tid >> 5;
  const int kc = kq >> 1;
  const int half = kq & 1;
  const int n4 = (tid & 31) * 4;

  const float* Bbase = Wf + (size_t)e * KTOT * NTOT + n0;
  const float* sbase = scale + (size_t)e * (KTOT / 128) * (NTOT / 128) + (n0 >> 7);

  f32x4 acc[4][4] = {};
  f32x4 v0[4], v1[4];

#define LOAD_B(KS, V)                                                          \
  {                                                                            \
    const float* Bk = Bbase + (size_t)((KS) * 64 + kq * 4) * NTOT + n4;        \
    _Pragma("unroll") for (int i = 0; i < 4; ++i)                              \
      V[i] = *(const f32x4*)(Bk + (size_t)i * NTOT);                           \
  }

#define ISSUE_A(KS)                                                            \
  {                                                                            \
    _Pragma("unroll") for (int i = 0; i < 4; ++i) {                            \
      __builtin_amdgcn_global_load_lds(                                        \
          (const __attribute__((address_space(1))) uint32*)(aSrc[i] + (size_t)(KS) * 128), \
          (__attribute__((address_space(3))) uint32*)(&As[(wid * 32 + i * 8) * 64]), \
          16, 0, 0);                                                           \
    }                                                                          \
  }

#define WRITE_B(KS, V)                                                         \
  {                                                                            \
    const float bscl = sbase[((KS) >> 1) * (NTOT / 128)];                      \
    _Pragma("unroll") for (int j = 0; j < 4; ++j) {                            \
      const int n = n4 + j;                                                    \
      const int key = (n & 7) ^ ((n >> 3) & 7);                                \
      uint32 lo = (uint32)bf16_of(V[0][j] * bscl) | ((uint32)bf16_of(V[1][j] * bscl) << 16); \
      uint32 hi = (uint32)bf16_of(V[2][j] * bscl) | ((uint32)bf16_of(V[3][j] * bscl) << 16); \
      *(u64t*)&Bs[n * 64 + ((kc ^ key) << 3) + half * 4] = (u64t)lo | ((u64t)hi << 32); \
    }                                                                          \
  }

#define MFMA_STEP()                                                            \
  {                                                                            \
    _Pragma("unroll") for (int sub = 0; sub < 2; ++sub) {                      \
      const int c0 = sub * 4 + (lane >> 4);                                    \
      bf16x8 a[4], b[4];                                                       \
      _Pragma("unroll") for (int fI = 0; fI < 4; ++fI) {                       \
        const int ra = wm * 64 + fI * 16 + (lane & 15);                        \
        const int ka = c0 ^ (ra & 7) ^ ((ra >> 3) & 7);                        \
        a[fI] = *(const bf16x8*)&As[ra * 64 + (ka << 3)];                      \
        const int rb = wn * 64 + fI * 16 + (lane & 15);                        \
        const int kb = c0 ^ (rb & 7) ^ ((rb >> 3) & 7);                        \
        b[fI] = *(const bf16x8*)&Bs[rb * 64 + (kb << 3)];                      \
      }                                                                        \
      _Pragma("unroll") for (int fm = 0; fm < 4; ++fm)                         \
        _Pragma("unroll") for (int fn = 0; fn < 4; ++fn)                       \
          acc[fm][fn] = __builtin_amdgcn_mfma_f32_16x16x32_bf16(a[fm], b[fn], acc[fm][fn], 0, 0, 0); \
    }                                                                          \
  }

  // ---- prologue: stage step 0; leave B(2)'s 4 loads in flight ----
  LOAD_B(0, v0);
  LOAD_B(1, v1);
  ISSUE_A(0);
  __builtin_amdgcn_sched_barrier(0);   // pin A-DMA issue before B(2) loads (FIFO)
  WRITE_B(0, v0);                      // implicit vmcnt wait retires B(0)
  LOAD_B(2, v0);
  asm volatile("s_waitcnt lgkmcnt(0)" ::: "memory");
  asm volatile("s_waitcnt vmcnt(4)" ::: "memory");   // retire B(1)+A(0); B(2) stays
  __builtin_amdgcn_s_barrier();

  for (int ks0 = 0; ks0 < NKS; ks0 += 2) {
    MFMA_STEP();                              // step ks0 (buffers: step ks0 data)
    __builtin_amdgcn_s_barrier();             // all reads of As/Bs done
    ISSUE_A(ks0 + 1);
    __builtin_amdgcn_sched_barrier(0);        // keep A-DMA oldest in vmem FIFO
    WRITE_B(ks0 + 1, v1);
    if (ks0 + 3 < NKS) LOAD_B(ks0 + 3, v1);
    asm volatile("s_waitcnt lgkmcnt(0)" ::: "memory");
    if (ks0 + 3 < NKS) asm volatile("s_waitcnt vmcnt(4)" ::: "memory");
    else               asm volatile("s_waitcnt vmcnt(0)" ::: "memory");
    __builtin_amdgcn_s_barrier();             // step ks0+1 data ready
    MFMA_STEP();                              // step ks0+1
    if (ks0 + 2 < NKS) {
      __builtin_amdgcn_s_barrier();
      ISSUE_A(ks0 + 2);
      __builtin_amdgcn_sched_barrier(0);
      WRITE_B(ks0 + 2, v0);
      if (ks0 + 4 < NKS) LOAD_B(ks0 + 4, v0);
      asm volatile("s_waitcnt lgkmcnt(0)" ::: "memory");
      if (ks0 + 4 < NKS) asm volatile("s_waitcnt vmcnt(4)" ::: "memory");
      else               asm volatile("s_waitcnt vmcnt(0)" ::: "memory");
      __builtin_amdgcn_s_barrier();
    }
  }
#undef LOAD_B
#undef ISSUE_A
#undef WRITE_B
#undef MFMA_STEP

  // ---- epilogue ----
  const int nbase = n0 + wn * 64;
#pragma unroll
  for (int fm = 0; fm < 4; ++fm) {
#pragma unroll
    for (int r2 = 0; r2 < 4; ++r2) {
      const int rl = row0 + wm * 64 + fm * 16 + (lane >> 4) * 4 + r2;
      const bool ok = rl < gsz;
      const int slot = off + rl;
      if constexpr (GEGLU) {
        const float p = ok ? s_prob[slot] : 0.f;
#pragma unroll
        for (int fn = 0; fn < 4; ++fn) {
          float vv = acc[fm][fn][r2];
          float vp = __shfl_xor(vv, 1, 64);  // pair even(gate)/odd(up) columns
          float g = (lane & 1) ? vp : vv;
          float u = (lane & 1) ? vv : vp;
          g = fminf(g, 7.f);
          u = fminf(fmaxf(u, -7.f), 7.f);
          const float sig = 1.f / (1.f + __expf(-1.702f * g));
          const float val = g * sig * (u + 1.f) * p;
          if (ok && !(lane & 1)) {
            const int c = (nbase + fn * 16 + (lane & 15)) >> 1;
            o_bf16[(size_t)slot * INTER_ + c] = bf16_of(val);
          }
        }
      } else {
        if (staged) {
          float* orow = o_f32 + (size_t)slot * DIM_;  // per-slot staging row
          if (ok) {
#pragma unroll
            for (int fn = 0; fn < 4; ++fn)
              orow[nbase + fn * 16 + (lane & 15)] = acc[fm][fn][r2];
          }
        } else {
          if (ok) {
            float* orow = o_f32 + (size_t)s_tok[slot] * DIM_;
#pragma unroll
            for (int fn = 0; fn < 4; ++fn)
              atomicAdd(&orow[nbase + fn * 16 + (lane & 15)], acc[fm][fn][r2]);
          }
        }
      }
    }
  }
}

// ---------------- reduce staged slot rows -> tokens ----------------
__global__ __launch_bounds__(256) void k_reduce(const float* __restrict__ o2s,
                                                const int* __restrict__ inv,
                                                float* __restrict__ out) {
  const int t = blockIdx.x;
  const int c = threadIdx.x * 8;
  f32x4 s0 = {0.f, 0.f, 0.f, 0.f}, s1 = {0.f, 0.f, 0.f, 0.f};
#pragma unroll
  for (int j = 0; j < 4; ++j) {
    const int sl = inv[t * 4 + j];
    if (sl >= 0) {
      const float* r = o2s + (size_t)sl * DIM_ + c;
      f32x4 a = *(const f32x4*)r;
      f32x4 b = *(const f32x4*)(r + 4);
      s0 += a; s1 += b;
    }
  }
  float* o = out + (size_t)t * DIM_ + c;
  *(f32x4*)o = s0;
  *(f32x4*)(o + 4) = s1;
}

extern "C" void kernel_launch(void* const* d_in, const int* in_sizes, int n_in,
                              void* d_out, int out_size, void* d_ws, size_t ws_size,
                              hipStream_t stream) {
  const float* x = (const float*)d_in[0];
  const void* tmask = d_in[1];
  const float* wts = (const float*)d_in[2];
  const int* idx = (const int*)d_in[3];
  const float* gup_w = (const float*)d_in[4];   // fp8 values widened to f32
  const float* dn_w = (const float*)d_in[5];
  const float* gup_sc = (const float*)d_in[6];
  const float* dn_sc = (const float*)d_in[7];
  float* out = (float*)d_out;
  char* ws = (char*)d_ws;

  const size_t xb_off = 262144;
  const size_t inter_off = xb_off + (size_t)NT_ * DIM_ * 2;
  const size_t o2s_off = inter_off + (size_t)(NE_ + 256) * INTER_ * 2;
  const size_t need = o2s_off;                                      // atomic path
  const size_t need2 = o2s_off + (size_t)(NE_ + 256) * DIM_ * 4;    // staged path
  if (ws_size < need) return;  // diagnostic: absmax ~488 => ws too small
  const int staged = (ws_size >= need2) ? 1 : 0;

  Meta* meta = (Meta*)(ws);
  int* s_tok = (int*)(ws + 4096);
  float* s_prob = (float*)(ws + 4096 + NE_ * 4);
  int* inv = (int*)(ws + 4096 + 2 * NE_ * 4);
  unsigned short* xb = (unsigned short*)(ws + xb_off);
  unsigned short* inter = (unsigned short*)(ws + inter_off);
  float* o2s = (float*)(ws + o2s_off);

  if (!staged)
    (void)hipMemsetAsync(d_out, 0, (size_t)out_size * sizeof(float), stream);
  hipLaunchKernelGGL(k_route_cast, dim3(1 + NT_ * DIM_ / 2048), dim3(256), 0, stream,
                     tmask, wts, idx, meta, s_tok, s_prob, inv, x, xb);
  hipLaunchKernelGGL((k_gemm<DIM_, UP_, true, true>), dim3((UP_ / 128) * MAXT), dim3(512), 0,
                     stream, gup_w, gup_sc, xb, meta, s_tok, s_prob, inter, (float*)nullptr, 0);
  hipLaunchKernelGGL((k_gemm<INTER_, DIM_, false, false>), dim3((DIM_ / 128) * MAXT), dim3(512), 0,
                     stream, dn_w, dn_sc, inter, meta, s_tok, s_prob, (unsigned short*)nullptr,
                     staged ? o2s : out, staged);
  if (staged)
    hipLaunchKernelGGL(k_reduce, dim3(NT_), dim3(256), 0, stream, o2s, inv, out);
}

// Round 29
// 755.923 us; speedup vs baseline: 1.0006x; 1.0006x over previous
//
#include <hip/hip_runtime.h>
#include <hip/hip_bf16.h>

#define E_ 32
#define DIM_ 2048
#define INTER_ 1408
#define UP_ 2816
#define NT_ 4096
#define NE_ 16384
#define MAXT 96   // row-tiles of 256: sum ceil(gs_e/256) <= 16384/256 + 32 = 96

typedef __attribute__((ext_vector_type(8))) short bf16x8;
typedef __attribute__((ext_vector_type(4))) float f32x4;
typedef unsigned int uint32;
typedef unsigned long long u64t;

struct Meta {
  int gs[E_];
  int offs[E_ + 1];
  int Ttot;
  int ntiles;
  int tile_e[MAXT];
  int tile_r0[MAXT];
};

__device__ __forceinline__ unsigned short bf16_of(float f) {
  union { __hip_bfloat16 b; unsigned short u; } cv;
  cv.b = __float2bfloat16(f);
  return cv.u;
}

__device__ __forceinline__ bool mask_ok(const void* m, int mode, int tok) {
  if (mode) return ((const uint32*)m)[tok] != 0u;
  return ((const unsigned char*)m)[tok] != 0;
}

// ---------------- fused: block 0 = routing sort; blocks 1.. = x f32->bf16 cast ----------------
__global__ __launch_bounds__(256) void k_route_cast(
    const void* __restrict__ tmask, const float* __restrict__ wts,
    const int* __restrict__ idx, Meta* __restrict__ meta,
    int* __restrict__ s_tok, float* __restrict__ s_prob, int* __restrict__ inv,
    const float* __restrict__ x, unsigned short* __restrict__ xb) {
  const int t = threadIdx.x;
  if (blockIdx.x != 0) {  // ---- xcast part ----
    const size_t i = ((size_t)(blockIdx.x - 1) * 256 + t) * 8;
    f32x4 a = *(const f32x4*)(x + i);
    f32x4 b = *(const f32x4*)(x + i + 4);
    uint4 o;
    o.x = (uint32)bf16_of(a.x) | ((uint32)bf16_of(a.y) << 16);
    o.y = (uint32)bf16_of(a.z) | ((uint32)bf16_of(a.w) << 16);
    o.z = (uint32)bf16_of(b.x) | ((uint32)bf16_of(b.y) << 16);
    o.w = (uint32)bf16_of(b.z) | ((uint32)bf16_of(b.w) << 16);
    *(uint4*)(xb + i) = o;
    return;
  }
  // ---- routing part (block 0 only) ----
  __shared__ unsigned short tc[E_][257];
  __shared__ int offs_s[E_ + 1];
  __shared__ int tot[E_];
  __shared__ int mmode;
  if (t == 0) {
    const uint32* w = (const uint32*)tmask;
    bool word_mode = true;
    for (int i = 0; i < 64; ++i) {
      uint32 v = w[i];
      if (!(v <= 1u || v == 0x3F800000u)) { word_mode = false; break; }
    }
    mmode = word_mode ? 1 : 0;
  }
#pragma unroll
  for (int e = 0; e < E_; ++e) tc[e][t] = 0;
  __syncthreads();
  const int base = t * 64;
  for (int i = 0; i < 64; ++i) {
    int ent = base + i;
    int e = idx[ent];
    bool v = mask_ok(tmask, mmode, ent >> 2) && (e >= 0) && (e < E_);
    if (v) tc[e][t] += 1;
  }
  __syncthreads();
  if (t < E_) {
    int run = 0;
    for (int j = 0; j < 256; ++j) {
      int c = tc[t][j]; tc[t][j] = (unsigned short)run; run += c;
    }
    tot[t] = run;
  }
  __syncthreads();
  if (t == 0) {
    int acc = 0, nt = 0;
    for (int e = 0; e < E_; ++e) {
      offs_s[e] = acc;
      meta->offs[e] = acc;
      meta->gs[e] = tot[e];
      for (int r0 = 0; r0 < tot[e]; r0 += 256) {
        meta->tile_e[nt] = e; meta->tile_r0[nt] = r0; ++nt;
      }
      acc += tot[e];
    }
    offs_s[E_] = acc;
    meta->offs[E_] = acc;
    meta->Ttot = acc;
    meta->ntiles = nt;
  }
  __syncthreads();
  for (int i = 0; i < 64; ++i) {
    int ent = base + i;
    int e = idx[ent];
    bool v = mask_ok(tmask, mmode, ent >> 2) && (e >= 0) && (e < E_);
    if (v) {
      int r = tc[e][t]++;
      int pos = offs_s[e] + r;
      s_tok[pos] = ent >> 2;
      s_prob[pos] = wts[ent];
      inv[ent] = pos;
    } else {
      inv[ent] = -1;
    }
  }
}

// ---------------- grouped GEMM: 256x128 tile, BK=64, counted-vmcnt (T4) ----------------
// Champion (r13/r16/r18/r20/r22-r28 lineage): GEMM1 444us, VGPR 96, no spills.
// Ledger: 10 surgeries, 1 win (counted vmcnt(4)), 8 losses, 1 null. Sharp
// local optimum of the 2-barrier family — do not perturb.
template <int KTOT, int NTOT, bool GEGLU, bool GATHER>
__global__ __launch_bounds__(512) void k_gemm(
    const float* __restrict__ Wf, const float* __restrict__ scale,
    const unsigned short* __restrict__ Asrc, const Meta* __restrict__ meta,
    const int* __restrict__ s_tok, const float* __restrict__ s_prob,
    unsigned short* __restrict__ o_bf16, float* __restrict__ o_f32, int staged) {
  constexpr int NX = NTOT / 128;
  constexpr int NKS = KTOT / 64;   // 32 (GEMM1), 22 (GEMM2): even, >= 4
  const int NBact = NX * meta->ntiles;
  const int bid = blockIdx.x;
  if (bid >= NBact) return;
  const int q = NBact >> 3, r = NBact & 7;
  const int x = bid & 7, pos = bid >> 3;
  const int wk = ((x < r) ? x * (q + 1) : r * (q + 1) + (x - r) * q) + pos;
  const int tile = wk / NX;
  const int n0 = (wk % NX) * 128;
  const int e = meta->tile_e[tile];
  const int row0 = meta->tile_r0[tile];
  const int off = meta->offs[e];
  const int gsz = meta->gs[e];

  __shared__ unsigned short As[256 * 64];
  __shared__ unsigned short Bs[128 * 64];

  const int tid = threadIdx.x;
  const int lane = tid & 63;
  const int wid = tid >> 6;
  const int wm = wid >> 1;
  const int wn = wid & 1;

  // ---- A gather source pointers (pre-swizzled global, linear LDS dest) ----
  const char* aSrc[4];
  {
    const int rr = lane >> 3, cc = lane & 7;
#pragma unroll
    for (int i = 0; i < 4; ++i) {
      const int grow = row0 + wid * 32 + i * 8 + rr;
      int slot;
      if (GATHER) slot = (grow < gsz) ? s_tok[off + grow] : 0;
      else slot = off + grow;
      const int key = rr ^ ((wid * 4 + i) & 7);
      aSrc[i] = (const char*)Asrc + (size_t)slot * (KTOT * 2) + ((cc ^ key) << 4);
    }
  }

  // ---- B staging role: thread -> (4 consecutive k, 4 n) ----
  const int kq = tid >> 5;
  const int kc = kq >> 1;
  const int half = kq & 1;
  const int n4 = (tid & 31) * 4;

  const float* Bbase = Wf + (size_t)e * KTOT * NTOT + n0;
  const float* sbase = scale + (size_t)e * (KTOT / 128) * (NTOT / 128) + (n0 >> 7);

  f32x4 acc[4][4] = {};
  f32x4 v0[4], v1[4];

#define LOAD_B(KS, V)                                                          \
  {                                                                            \
    const float* Bk = Bbase + (size_t)((KS) * 64 + kq * 4) * NTOT + n4;        \
    _Pragma("unroll") for (int i = 0; i < 4; ++i)                              \
      V[i] = *(const f32x4*)(Bk + (size_t)i * NTOT);                           \
  }

#define ISSUE_A(KS)                                                            \
  {                                                                            \
    _Pragma("unroll") for (int i = 0; i < 4; ++i) {                            \
      __builtin_amdgcn_global_load_lds(                                        \
          (const __attribute__((address_space(1))) uint32*)(aSrc[i] + (size_t)(KS) * 128), \
          (__attribute__((address_space(3))) uint32*)(&As[(wid * 32 + i * 8) * 64]), \
          16, 0, 0);                                                           \
    }                                                                          \
  }

#define WRITE_B(KS, V)                                                         \
  {                                                                            \
    const float bscl = sbase[((KS) >> 1) * (NTOT / 128)];                      \
    _Pragma("unroll") for (int j = 0; j < 4; ++j) {                            \
      const int n = n4 + j;                                                    \
      const int key = (n & 7) ^ ((n >> 3) & 7);                                \
      uint32 lo = (uint32)bf16_of(V[0][j] * bscl) | ((uint32)bf16_of(V[1][j] * bscl) << 16); \
      uint32 hi = (uint32)bf16_of(V[2][j] * bscl) | ((uint32)bf16_of(V[3][j] * bscl) << 16); \
      *(u64t*)&Bs[n * 64 + ((kc ^ key) << 3) + half * 4] = (u64t)lo | ((u64t)hi << 32); \
    }                                                                          \
  }

#define MFMA_STEP()                                                            \
  {                                                                            \
    _Pragma("unroll") for (int sub = 0; sub < 2; ++sub) {                      \
      const int c0 = sub * 4 + (lane >> 4);                                    \
      bf16x8 a[4], b[4];                                                       \
      _Pragma("unroll") for (int fI = 0; fI < 4; ++fI) {                       \
        const int ra = wm * 64 + fI * 16 + (lane & 15);                        \
        const int ka = c0 ^ (ra & 7) ^ ((ra >> 3) & 7);                        \
        a[fI] = *(const bf16x8*)&As[ra * 64 + (ka << 3)];                      \
        const int rb = wn * 64 + fI * 16 + (lane & 15);                        \
        const int kb = c0 ^ (rb & 7) ^ ((rb >> 3) & 7);                        \
        b[fI] = *(const bf16x8*)&Bs[rb * 64 + (kb << 3)];                      \
      }                                                                        \
      _Pragma("unroll") for (int fm = 0; fm < 4; ++fm)                         \
        _Pragma("unroll") for (int fn = 0; fn < 4; ++fn)                       \
          acc[fm][fn] = __builtin_amdgcn_mfma_f32_16x16x32_bf16(a[fm], b[fn], acc[fm][fn], 0, 0, 0); \
    }                                                                          \
  }

  // ---- prologue: stage step 0; leave B(2)'s 4 loads in flight ----
  LOAD_B(0, v0);
  LOAD_B(1, v1);
  ISSUE_A(0);
  __builtin_amdgcn_sched_barrier(0);   // pin A-DMA issue before B(2) loads (FIFO)
  WRITE_B(0, v0);                      // implicit vmcnt wait retires B(0)
  LOAD_B(2, v0);
  asm volatile("s_waitcnt lgkmcnt(0)" ::: "memory");
  asm volatile("s_waitcnt vmcnt(4)" ::: "memory");   // retire B(1)+A(0); B(2) stays
  __builtin_amdgcn_s_barrier();

  for (int ks0 = 0; ks0 < NKS; ks0 += 2) {
    MFMA_STEP();                              // step ks0 (buffers: step ks0 data)
    __builtin_amdgcn_s_barrier();             // all reads of As/Bs done
    ISSUE_A(ks0 + 1);
    __builtin_amdgcn_sched_barrier(0);        // keep A-DMA oldest in vmem FIFO
    WRITE_B(ks0 + 1, v1);
    if (ks0 + 3 < NKS) LOAD_B(ks0 + 3, v1);
    asm volatile("s_waitcnt lgkmcnt(0)" ::: "memory");
    if (ks0 + 3 < NKS) asm volatile("s_waitcnt vmcnt(4)" ::: "memory");
    else               asm volatile("s_waitcnt vmcnt(0)" ::: "memory");
    __builtin_amdgcn_s_barrier();             // step ks0+1 data ready
    MFMA_STEP();                              // step ks0+1
    if (ks0 + 2 < NKS) {
      __builtin_amdgcn_s_barrier();
      ISSUE_A(ks0 + 2);
      __builtin_amdgcn_sched_barrier(0);
      WRITE_B(ks0 + 2, v0);
      if (ks0 + 4 < NKS) LOAD_B(ks0 + 4, v0);
      asm volatile("s_waitcnt lgkmcnt(0)" ::: "memory");
      if (ks0 + 4 < NKS) asm volatile("s_waitcnt vmcnt(4)" ::: "memory");
      else               asm volatile("s_waitcnt vmcnt(0)" ::: "memory");
      __builtin_amdgcn_s_barrier();
    }
  }
#undef LOAD_B
#undef ISSUE_A
#undef WRITE_B
#undef MFMA_STEP

  // ---- epilogue ----
  const int nbase = n0 + wn * 64;
#pragma unroll
  for (int fm = 0; fm < 4; ++fm) {
#pragma unroll
    for (int r2 = 0; r2 < 4; ++r2) {
      const int rl = row0 + wm * 64 + fm * 16 + (lane >> 4) * 4 + r2;
      const bool ok = rl < gsz;
      const int slot = off + rl;
      if constexpr (GEGLU) {
        const float p = ok ? s_prob[slot] : 0.f;
#pragma unroll
        for (int fn = 0; fn < 4; ++fn) {
          float vv = acc[fm][fn][r2];
          float vp = __shfl_xor(vv, 1, 64);  // pair even(gate)/odd(up) columns
          float g = (lane & 1) ? vp : vv;
          float u = (lane & 1) ? vv : vp;
          g = fminf(g, 7.f);
          u = fminf(fmaxf(u, -7.f), 7.f);
          const float sig = 1.f / (1.f + __expf(-1.702f * g));
          const float val = g * sig * (u + 1.f) * p;
          if (ok && !(lane & 1)) {
            const int c = (nbase + fn * 16 + (lane & 15)) >> 1;
            o_bf16[(size_t)slot * INTER_ + c] = bf16_of(val);
          }
        }
      } else {
        if (staged) {
          float* orow = o_f32 + (size_t)slot * DIM_;  // per-slot staging row
          if (ok) {
#pragma unroll
            for (int fn = 0; fn < 4; ++fn)
              orow[nbase + fn * 16 + (lane & 15)] = acc[fm][fn][r2];
          }
        } else {
          if (ok) {
            float* orow = o_f32 + (size_t)s_tok[slot] * DIM_;
#pragma unroll
            for (int fn = 0; fn < 4; ++fn)
              atomicAdd(&orow[nbase + fn * 16 + (lane & 15)], acc[fm][fn][r2]);
          }
        }
      }
    }
  }
}

// ---------------- reduce staged slot rows -> tokens ----------------
__global__ __launch_bounds__(256) void k_reduce(const float* __restrict__ o2s,
                                                const int* __restrict__ inv,
                                                float* __restrict__ out) {
  const int t = blockIdx.x;
  const int c = threadIdx.x * 8;
  f32x4 s0 = {0.f, 0.f, 0.f, 0.f}, s1 = {0.f, 0.f, 0.f, 0.f};
#pragma unroll
  for (int j = 0; j < 4; ++j) {
    const int sl = inv[t * 4 + j];
    if (sl >= 0) {
      const float* r = o2s + (size_t)sl * DIM_ + c;
      f32x4 a = *(const f32x4*)r;
      f32x4 b = *(const f32x4*)(r + 4);
      s0 += a; s1 += b;
    }
  }
  float* o = out + (size_t)t * DIM_ + c;
  *(f32x4*)o = s0;
  *(f32x4*)(o + 4) = s1;
}

extern "C" void kernel_launch(void* const* d_in, const int* in_sizes, int n_in,
                              void* d_out, int out_size, void* d_ws, size_t ws_size,
                              hipStream_t stream) {
  const float* x = (const float*)d_in[0];
  const void* tmask = d_in[1];
  const float* wts = (const float*)d_in[2];
  const int* idx = (const int*)d_in[3];
  const float* gup_w = (const float*)d_in[4];   // fp8 values widened to f32
  const float* dn_w = (const float*)d_in[5];
  const float* gup_sc = (const float*)d_in[6];
  const float* dn_sc = (const float*)d_in[7];
  float* out = (float*)d_out;
  char* ws = (char*)d_ws;

  const size_t xb_off = 262144;
  const size_t inter_off = xb_off + (size_t)NT_ * DIM_ * 2;
  const size_t o2s_off = inter_off + (size_t)(NE_ + 256) * INTER_ * 2;
  const size_t need = o2s_off;                                      // atomic path
  const size_t need2 = o2s_off + (size_t)(NE_ + 256) * DIM_ * 4;    // staged path
  if (ws_size < need) return;  // diagnostic: absmax ~488 => ws too small
  const int staged = (ws_size >= need2) ? 1 : 0;

  Meta* meta = (Meta*)(ws);
  int* s_tok = (int*)(ws + 4096);
  float* s_prob = (float*)(ws + 4096 + NE_ * 4);
  int* inv = (int*)(ws + 4096 + 2 * NE_ * 4);
  unsigned short* xb = (unsigned short*)(ws + xb_off);
  unsigned short* inter = (unsigned short*)(ws + inter_off);
  float* o2s = (float*)(ws + o2s_off);

  if (!staged)
    (void)hipMemsetAsync(d_out, 0, (size_t)out_size * sizeof(float), stream);
  hipLaunchKernelGGL(k_route_cast, dim3(1 + NT_ * DIM_ / 2048), dim3(256), 0, stream,
                     tmask, wts, idx, meta, s_tok, s_prob, inv, x, xb);
  hipLaunchKernelGGL((k_gemm<DIM_, UP_, true, true>), dim3((UP_ / 128) * MAXT), dim3(512), 0,
                     stream, gup_w, gup_sc, xb, meta, s_tok, s_prob, inter, (float*)nullptr, 0);
  hipLaunchKernelGGL((k_gemm<INTER_, DIM_, false, false>), dim3((DIM_ / 128) * MAXT), dim3(512), 0,
                     stream, dn_w, dn_sc, inter, meta, s_tok, s_prob, (unsigned short*)nullptr,
                     staged ? o2s : out, staged);
  if (staged)
    hipLaunchKernelGGL(k_reduce, dim3(NT_), dim3(256), 0, stream, o2s, inv, out);
}

// Round 30
// 755.147 us; speedup vs baseline: 1.0017x; 1.0010x over previous
//
#include <hip/hip_runtime.h>
#include <hip/hip_bf16.h>

#define E_ 32
#define DIM_ 2048
#define INTER_ 1408
#define UP_ 2816
#define NT_ 4096
#define NE_ 16384
#define MAXT 96   // row-tiles of 256: sum ceil(gs_e/256) <= 16384/256 + 32 = 96

typedef __attribute__((ext_vector_type(8))) short bf16x8;
typedef __attribute__((ext_vector_type(4))) float f32x4;
typedef unsigned int uint32;
typedef unsigned long long u64t;

struct Meta {
  int gs[E_];
  int offs[E_ + 1];
  int Ttot;
  int ntiles;
  int tile_e[MAXT];
  int tile_r0[MAXT];
};

__device__ __forceinline__ unsigned short bf16_of(float f) {
  union { __hip_bfloat16 b; unsigned short u; } cv;
  cv.b = __float2bfloat16(f);
  return cv.u;
}

__device__ __forceinline__ bool mask_ok(const void* m, int mode, int tok) {
  if (mode) return ((const uint32*)m)[tok] != 0u;
  return ((const unsigned char*)m)[tok] != 0;
}

// ---------------- fused: block 0 = routing sort; blocks 1.. = x f32->bf16 cast ----------------
__global__ __launch_bounds__(256) void k_route_cast(
    const void* __restrict__ tmask, const float* __restrict__ wts,
    const int* __restrict__ idx, Meta* __restrict__ meta,
    int* __restrict__ s_tok, float* __restrict__ s_prob, int* __restrict__ inv,
    const float* __restrict__ x, unsigned short* __restrict__ xb) {
  const int t = threadIdx.x;
  if (blockIdx.x != 0) {  // ---- xcast part ----
    const size_t i = ((size_t)(blockIdx.x - 1) * 256 + t) * 8;
    f32x4 a = *(const f32x4*)(x + i);
    f32x4 b = *(const f32x4*)(x + i + 4);
    uint4 o;
    o.x = (uint32)bf16_of(a.x) | ((uint32)bf16_of(a.y) << 16);
    o.y = (uint32)bf16_of(a.z) | ((uint32)bf16_of(a.w) << 16);
    o.z = (uint32)bf16_of(b.x) | ((uint32)bf16_of(b.y) << 16);
    o.w = (uint32)bf16_of(b.z) | ((uint32)bf16_of(b.w) << 16);
    *(uint4*)(xb + i) = o;
    return;
  }
  // ---- routing part (block 0 only) ----
  __shared__ unsigned short tc[E_][257];
  __shared__ int offs_s[E_ + 1];
  __shared__ int tot[E_];
  __shared__ int mmode;
  if (t == 0) {
    const uint32* w = (const uint32*)tmask;
    bool word_mode = true;
    for (int i = 0; i < 64; ++i) {
      uint32 v = w[i];
      if (!(v <= 1u || v == 0x3F800000u)) { word_mode = false; break; }
    }
    mmode = word_mode ? 1 : 0;
  }
#pragma unroll
  for (int e = 0; e < E_; ++e) tc[e][t] = 0;
  __syncthreads();
  const int base = t * 64;
  for (int i = 0; i < 64; ++i) {
    int ent = base + i;
    int e = idx[ent];
    bool v = mask_ok(tmask, mmode, ent >> 2) && (e >= 0) && (e < E_);
    if (v) tc[e][t] += 1;
  }
  __syncthreads();
  if (t < E_) {
    int run = 0;
    for (int j = 0; j < 256; ++j) {
      int c = tc[t][j]; tc[t][j] = (unsigned short)run; run += c;
    }
    tot[t] = run;
  }
  __syncthreads();
  if (t == 0) {
    int acc = 0, nt = 0;
    for (int e = 0; e < E_; ++e) {
      offs_s[e] = acc;
      meta->offs[e] = acc;
      meta->gs[e] = tot[e];
      for (int r0 = 0; r0 < tot[e]; r0 += 256) {
        meta->tile_e[nt] = e; meta->tile_r0[nt] = r0; ++nt;
      }
      acc += tot[e];
    }
    offs_s[E_] = acc;
    meta->offs[E_] = acc;
    meta->Ttot = acc;
    meta->ntiles = nt;
  }
  __syncthreads();
  for (int i = 0; i < 64; ++i) {
    int ent = base + i;
    int e = idx[ent];
    bool v = mask_ok(tmask, mmode, ent >> 2) && (e >= 0) && (e < E_);
    if (v) {
      int r = tc[e][t]++;
      int pos = offs_s[e] + r;
      s_tok[pos] = ent >> 2;
      s_prob[pos] = wts[ent];
      inv[ent] = pos;
    } else {
      inv[ent] = -1;
    }
  }
}

// ---------------- grouped GEMM: 256x128 tile, BK=64, counted-vmcnt (T4) ----------------
// Champion (r13/r16/r18/r20/r22-r29 lineage): GEMM1 444us, VGPR 96, no spills.
// Ledger: 10 surgeries, 1 win (counted vmcnt(4)), 8 losses, 1 null. Sharp
// local optimum of the 2-barrier family — do not perturb.
template <int KTOT, int NTOT, bool GEGLU, bool GATHER>
__global__ __launch_bounds__(512) void k_gemm(
    const float* __restrict__ Wf, const float* __restrict__ scale,
    const unsigned short* __restrict__ Asrc, const Meta* __restrict__ meta,
    const int* __restrict__ s_tok, const float* __restrict__ s_prob,
    unsigned short* __restrict__ o_bf16, float* __restrict__ o_f32, int staged) {
  constexpr int NX = NTOT / 128;
  constexpr int NKS = KTOT / 64;   // 32 (GEMM1), 22 (GEMM2): even, >= 4
  const int NBact = NX * meta->ntiles;
  const int bid = blockIdx.x;
  if (bid >= NBact) return;
  const int q = NBact >> 3, r = NBact & 7;
  const int x = bid & 7, pos = bid >> 3;
  const int wk = ((x < r) ? x * (q + 1) : r * (q + 1) + (x - r) * q) + pos;
  const int tile = wk / NX;
  const int n0 = (wk % NX) * 128;
  const int e = meta->tile_e[tile];
  const int row0 = meta->tile_r0[tile];
  const int off = meta->offs[e];
  const int gsz = meta->gs[e];

  __shared__ unsigned short As[256 * 64];
  __shared__ unsigned short Bs[128 * 64];

  const int tid = threadIdx.x;
  const int lane = tid & 63;
  const int wid = tid >> 6;
  const int wm = wid >> 1;
  const int wn = wid & 1;

  // ---- A gather source pointers (pre-swizzled global, linear LDS dest) ----
  const char* aSrc[4];
  {
    const int rr = lane >> 3, cc = lane & 7;
#pragma unroll
    for (int i = 0; i < 4; ++i) {
      const int grow = row0 + wid * 32 + i * 8 + rr;
      int slot;
      if (GATHER) slot = (grow < gsz) ? s_tok[off + grow] : 0;
      else slot = off + grow;
      const int key = rr ^ ((wid * 4 + i) & 7);
      aSrc[i] = (const char*)Asrc + (size_t)slot * (KTOT * 2) + ((cc ^ key) << 4);
    }
  }

  // ---- B staging role: thread -> (4 consecutive k, 4 n) ----
  const int kq = tid >> 5;
  const int kc = kq >> 1;
  const int half = kq & 1;
  const int n4 = (tid & 31) * 4;

  const float* Bbase = Wf + (size_t)e * KTOT * NTOT + n0;
  const float* sbase = scale + (size_t)e * (KTOT / 128) * (NTOT / 128) + (n0 >> 7);

  f32x4 acc[4][4] = {};
  f32x4 v0[4], v1[4];

#define LOAD_B(KS, V)                                                          \
  {                                                                            \
    const float* Bk = Bbase + (size_t)((KS) * 64 + kq * 4) * NTOT + n4;        \
    _Pragma("unroll") for (int i = 0; i < 4; ++i)                              \
      V[i] = *(const f32x4*)(Bk + (size_t)i * NTOT);                           \
  }

#define ISSUE_A(KS)                                                            \
  {                                                                            \
    _Pragma("unroll") for (int i = 0; i < 4; ++i) {                            \
      __builtin_amdgcn_global_load_lds(                                        \
          (const __attribute__((address_space(1))) uint32*)(aSrc[i] + (size_t)(KS) * 128), \
          (__attribute__((address_space(3))) uint32*)(&As[(wid * 32 + i * 8) * 64]), \
          16, 0, 0);                                                           \
    }                                                                          \
  }

#define WRITE_B(KS, V)                                                         \
  {                                                                            \
    const float bscl = sbase[((KS) >> 1) * (NTOT / 128)];                      \
    _Pragma("unroll") for (int j = 0; j < 4; ++j) {                            \
      const int n = n4 + j;                                                    \
      const int key = (n & 7) ^ ((n >> 3) & 7);                                \
      uint32 lo = (uint32)bf16_of(V[0][j] * bscl) | ((uint32)bf16_of(V[1][j] * bscl) << 16); \
      uint32 hi = (uint32)bf16_of(V[2][j] * bscl) | ((uint32)bf16_of(V[3][j] * bscl) << 16); \
      *(u64t*)&Bs[n * 64 + ((kc ^ key) << 3) + half * 4] = (u64t)lo | ((u64t)hi << 32); \
    }                                                                          \
  }

#define MFMA_STEP()                                                            \
  {                                                                            \
    _Pragma("unroll") for (int sub = 0; sub < 2; ++sub) {                      \
      const int c0 = sub * 4 + (lane >> 4);                                    \
      bf16x8 a[4], b[4];                                                       \
      _Pragma("unroll") for (int fI = 0; fI < 4; ++fI) {                       \
        const int ra = wm * 64 + fI * 16 + (lane & 15);                        \
        const int ka = c0 ^ (ra & 7) ^ ((ra >> 3) & 7);                        \
        a[fI] = *(const bf16x8*)&As[ra * 64 + (ka << 3)];                      \
        const int rb = wn * 64 + fI * 16 + (lane & 15);                        \
        const int kb = c0 ^ (rb & 7) ^ ((rb >> 3) & 7);                        \
        b[fI] = *(const bf16x8*)&Bs[rb * 64 + (kb << 3)];                      \
      }                                                                        \
      _Pragma("unroll") for (int fm = 0; fm < 4; ++fm)                         \
        _Pragma("unroll") for (int fn = 0; fn < 4; ++fn)                       \
          acc[fm][fn] = __builtin_amdgcn_mfma_f32_16x16x32_bf16(a[fm], b[fn], acc[fm][fn], 0, 0, 0); \
    }                                                                          \
  }

  // ---- prologue: stage step 0; leave B(2)'s 4 loads in flight ----
  LOAD_B(0, v0);
  LOAD_B(1, v1);
  ISSUE_A(0);
  __builtin_amdgcn_sched_barrier(0);   // pin A-DMA issue before B(2) loads (FIFO)
  WRITE_B(0, v0);                      // implicit vmcnt wait retires B(0)
  LOAD_B(2, v0);
  asm volatile("s_waitcnt lgkmcnt(0)" ::: "memory");
  asm volatile("s_waitcnt vmcnt(4)" ::: "memory");   // retire B(1)+A(0); B(2) stays
  __builtin_amdgcn_s_barrier();

  for (int ks0 = 0; ks0 < NKS; ks0 += 2) {
    MFMA_STEP();                              // step ks0 (buffers: step ks0 data)
    __builtin_amdgcn_s_barrier();             // all reads of As/Bs done
    ISSUE_A(ks0 + 1);
    __builtin_amdgcn_sched_barrier(0);        // keep A-DMA oldest in vmem FIFO
    WRITE_B(ks0 + 1, v1);
    if (ks0 + 3 < NKS) LOAD_B(ks0 + 3, v1);
    asm volatile("s_waitcnt lgkmcnt(0)" ::: "memory");
    if (ks0 + 3 < NKS) asm volatile("s_waitcnt vmcnt(4)" ::: "memory");
    else               asm volatile("s_waitcnt vmcnt(0)" ::: "memory");
    __builtin_amdgcn_s_barrier();             // step ks0+1 data ready
    MFMA_STEP();                              // step ks0+1
    if (ks0 + 2 < NKS) {
      __builtin_amdgcn_s_barrier();
      ISSUE_A(ks0 + 2);
      __builtin_amdgcn_sched_barrier(0);
      WRITE_B(ks0 + 2, v0);
      if (ks0 + 4 < NKS) LOAD_B(ks0 + 4, v0);
      asm volatile("s_waitcnt lgkmcnt(0)" ::: "memory");
      if (ks0 + 4 < NKS) asm volatile("s_waitcnt vmcnt(4)" ::: "memory");
      else               asm volatile("s_waitcnt vmcnt(0)" ::: "memory");
      __builtin_amdgcn_s_barrier();
    }
  }
#undef LOAD_B
#undef ISSUE_A
#undef WRITE_B
#undef MFMA_STEP

  // ---- epilogue ----
  const int nbase = n0 + wn * 64;
#pragma unroll
  for (int fm = 0; fm < 4; ++fm) {
#pragma unroll
    for (int r2 = 0; r2 < 4; ++r2) {
      const int rl = row0 + wm * 64 + fm * 16 + (lane >> 4) * 4 + r2;
      const bool ok = rl < gsz;
      const int slot = off + rl;
      if constexpr (GEGLU) {
        const float p = ok ? s_prob[slot] : 0.f;
#pragma unroll
        for (int fn = 0; fn < 4; ++fn) {
          float vv = acc[fm][fn][r2];
          float vp = __shfl_xor(vv, 1, 64);  // pair even(gate)/odd(up) columns
          float g = (lane & 1) ? vp : vv;
          float u = (lane & 1) ? vv : vp;
          g = fminf(g, 7.f);
          u = fminf(fmaxf(u, -7.f), 7.f);
          const float sig = 1.f / (1.f + __expf(-1.702f * g));
          const float val = g * sig * (u + 1.f) * p;
          if (ok && !(lane & 1)) {
            const int c = (nbase + fn * 16 + (lane & 15)) >> 1;
            o_bf16[(size_t)slot * INTER_ + c] = bf16_of(val);
          }
        }
      } else {
        if (staged) {
          float* orow = o_f32 + (size_t)slot * DIM_;  // per-slot staging row
          if (ok) {
#pragma unroll
            for (int fn = 0; fn < 4; ++fn)
              orow[nbase + fn * 16 + (lane & 15)] = acc[fm][fn][r2];
          }
        } else {
          if (ok) {
            float* orow = o_f32 + (size_t)s_tok[slot] * DIM_;
#pragma unroll
            for (int fn = 0; fn < 4; ++fn)
              atomicAdd(&orow[nbase + fn * 16 + (lane & 15)], acc[fm][fn][r2]);
          }
        }
      }
    }
  }
}

// ---------------- reduce staged slot rows -> tokens ----------------
__global__ __launch_bounds__(256) void k_reduce(const float* __restrict__ o2s,
                                                const int* __restrict__ inv,
                                                float* __restrict__ out) {
  const int t = blockIdx.x;
  const int c = threadIdx.x * 8;
  f32x4 s0 = {0.f, 0.f, 0.f, 0.f}, s1 = {0.f, 0.f, 0.f, 0.f};
#pragma unroll
  for (int j = 0; j < 4; ++j) {
    const int sl = inv[t * 4 + j];
    if (sl >= 0) {
      const float* r = o2s + (size_t)sl * DIM_ + c;
      f32x4 a = *(const f32x4*)r;
      f32x4 b = *(const f32x4*)(r + 4);
      s0 += a; s1 += b;
    }
  }
  float* o = out + (size_t)t * DIM_ + c;
  *(f32x4*)o = s0;
  *(f32x4*)(o + 4) = s1;
}

extern "C" void kernel_launch(void* const* d_in, const int* in_sizes, int n_in,
                              void* d_out, int out_size, void* d_ws, size_t ws_size,
                              hipStream_t stream) {
  const float* x = (const float*)d_in[0];
  const void* tmask = d_in[1];
  const float* wts = (const float*)d_in[2];
  const int* idx = (const int*)d_in[3];
  const float* gup_w = (const float*)d_in[4];   // fp8 values widened to f32
  const float* dn_w = (const float*)d_in[5];
  const float* gup_sc = (const float*)d_in[6];
  const float* dn_sc = (const float*)d_in[7];
  float* out = (float*)d_out;
  char* ws = (char*)d_ws;

  const size_t xb_off = 262144;
  const size_t inter_off = xb_off + (size_t)NT_ * DIM_ * 2;
  const size_t o2s_off = inter_off + (size_t)(NE_ + 256) * INTER_ * 2;
  const size_t need = o2s_off;                                      // atomic path
  const size_t need2 = o2s_off + (size_t)(NE_ + 256) * DIM_ * 4;    // staged path
  if (ws_size < need) return;  // diagnostic: absmax ~488 => ws too small
  const int staged = (ws_size >= need2) ? 1 : 0;

  Meta* meta = (Meta*)(ws);
  int* s_tok = (int*)(ws + 4096);
  float* s_prob = (float*)(ws + 4096 + NE_ * 4);
  int* inv = (int*)(ws + 4096 + 2 * NE_ * 4);
  unsigned short* xb = (unsigned short*)(ws + xb_off);
  unsigned short* inter = (unsigned short*)(ws + inter_off);
  float* o2s = (float*)(ws + o2s_off);

  if (!staged)
    (void)hipMemsetAsync(d_out, 0, (size_t)out_size * sizeof(float), stream);
  hipLaunchKernelGGL(k_route_cast, dim3(1 + NT_ * DIM_ / 2048), dim3(256), 0, stream,
                     tmask, wts, idx, meta, s_tok, s_prob, inv, x, xb);
  hipLaunchKernelGGL((k_gemm<DIM_, UP_, true, true>), dim3((UP_ / 128) * MAXT), dim3(512), 0,
                     stream, gup_w, gup_sc, xb, meta, s_tok, s_prob, inter, (float*)nullptr, 0);
  hipLaunchKernelGGL((k_gemm<INTER_, DIM_, false, false>), dim3((DIM_ / 128) * MAXT), dim3(512), 0,
                     stream, dn_w, dn_sc, inter, meta, s_tok, s_prob, (unsigned short*)nullptr,
                     staged ? o2s : out, staged);
  if (staged)
    hipLaunchKernelGGL(k_reduce, dim3(NT_), dim3(256), 0, stream, o2s, inv, out);
}